// Round 1
// baseline (2658.438 us; speedup 1.0000x reference)
//
#include <hip/hip_runtime.h>

// SheafGluingPoly: out = sum_k poly[k] * (L^k c0), L = sheaf Laplacian over E edges.
// B=4, M=50000, D=8, E=1.6e6, LAM=1.0, POLY_K=3.
//
// v2: CSR gather formulation. The previous scatter kernel was limited by
// 102.4M scalar float atomicAdd messages/dispatch (WRITE_SIZE=409.6MB at 26%
// HBM, VALU 14%). Here we build a node->incidence CSR once per launch (int
// atomics only, 3.2M), then one 64-lane warp per node gathers contributions
// with exclusive ownership of its output: no float atomics, no acc memsets,
// and the init/axpy polynomial update is fused into the gather epilogue.

#define BLOCK 256

__global__ __launch_bounds__(BLOCK) void hist_kernel(
    const int* __restrict__ src, const int* __restrict__ dst,
    int* __restrict__ cnt, int E)
{
    int i = blockIdx.x * BLOCK + threadIdx.x;
    if (i >= E) return;
    atomicAdd(&cnt[src[i]], 1);
    atomicAdd(&cnt[dst[i]], 1);
}

// Exclusive prefix sum over M counts -> off (bucket starts) and cur (fill cursors).
// Single block; M=50K so ~196 elements/thread, trivial cost (~10us).
__global__ __launch_bounds__(BLOCK) void scan_kernel(
    const int* __restrict__ cnt, int* __restrict__ off, int* __restrict__ cur, int M)
{
    __shared__ int sums[BLOCK];
    int tid = threadIdx.x;
    int chunk = (M + BLOCK - 1) / BLOCK;
    int lo = tid * chunk;
    int hi = lo + chunk; if (hi > M) hi = M;
    int s = 0;
    for (int i = lo; i < hi; i++) s += cnt[i];
    sums[tid] = s;
    __syncthreads();
    if (tid == 0) {
        int run = 0;
        for (int i = 0; i < BLOCK; i++) { int v = sums[i]; sums[i] = run; run += v; }
    }
    __syncthreads();
    int run = sums[tid];
    for (int i = lo; i < hi; i++) {
        int v = cnt[i];
        off[i] = run;
        cur[i] = run;
        run += v;
    }
}

// Fill incidence lists. Entry = {e<<1 | side, other_node}. After this kernel,
// cur[m] == off[m] + degree(m), i.e. the bucket end (reused by gather).
__global__ __launch_bounds__(BLOCK) void fill_kernel(
    const int* __restrict__ src, const int* __restrict__ dst,
    int* __restrict__ cur, int2* __restrict__ idx, int E)
{
    int i = blockIdx.x * BLOCK + threadIdx.x;
    if (i >= E) return;
    int s = src[i], d = dst[i];
    int ps = atomicAdd(&cur[s], 1);
    idx[ps] = make_int2(i << 1, d);         // m is src side; other = dst
    int pd = atomicAdd(&cur[d], 1);
    idx[pd] = make_int2((i << 1) | 1, s);   // m is dst side; other = src
}

// One 64-lane warp per node m. lane = slot*32 + b*8 + a:
//   slot in {0,1}: two incidences processed per loop iteration
//   b: batch, a: row index of R (and, after the final transpose-reduce, the
//      output component written by this lane).
// Per incidence (edge e, side): r[b][a] = Rs[e][a]·p[b][src] - Rd[e][a]·p[b][dst];
// contribution to acc[b][m][d] is +Rs[e][a][d]*r (side=src) or -Rd[e][a][d]*r.
// Sum over a is deferred to a per-node butterfly so the loop body has no
// cross-lane ops. Epilogue fuses the polynomial update:
//   k==1: out = poly[0]*c0 + poly[1]*acc; k>1: out += poly[k]*acc.
__global__ __launch_bounds__(BLOCK) void gather_kernel(
    const float* __restrict__ p,
    const float* __restrict__ Rs, const float* __restrict__ Rd,
    const int* __restrict__ off, const int* __restrict__ endo,
    const int2* __restrict__ idx,
    const float* __restrict__ poly, int k,
    const float* __restrict__ c0,
    float* __restrict__ acc, float* __restrict__ out,
    int M)
{
    int gw = (int)((blockIdx.x * BLOCK + threadIdx.x) >> 6);
    if (gw >= M) return;
    int m = gw;
    int lane = threadIdx.x & 63;
    int slot = lane >> 5;
    int b = (lane >> 3) & 3;
    int a = lane & 7;

    const float* pbase = p + (size_t)b * M * 8;
    const float* pm = pbase + (size_t)m * 8;
    float4 m0 = *(const float4*)pm;
    float4 m1 = *(const float4*)(pm + 4);

    float av0 = 0.f, av1 = 0.f, av2 = 0.f, av3 = 0.f;
    float av4 = 0.f, av5 = 0.f, av6 = 0.f, av7 = 0.f;

    int s0 = off[m];
    int s1 = endo[m];
    int arow = a * 8;

    for (int it = s0 + slot; it < s1; it += 2) {
        int2 en = idx[it];
        int e = en.x >> 1;
        bool isDst = (en.x & 1) != 0;
        int other = en.y;

        const float* rp = Rs + (size_t)e * 64 + arow;
        float4 A0 = *(const float4*)rp;
        float4 A1 = *(const float4*)(rp + 4);
        const float* dp = Rd + (size_t)e * 64 + arow;
        float4 B0 = *(const float4*)dp;
        float4 B1 = *(const float4*)(dp + 4);
        const float* po = pbase + (size_t)other * 8;
        float4 P0 = *(const float4*)po;
        float4 P1 = *(const float4*)(po + 4);

        // Four dots, then select by side (keeps the 32-lane slot branch-free).
        float rAm = A0.x*m0.x + A0.y*m0.y + A0.z*m0.z + A0.w*m0.w
                  + A1.x*m1.x + A1.y*m1.y + A1.z*m1.z + A1.w*m1.w;
        float rAP = A0.x*P0.x + A0.y*P0.y + A0.z*P0.z + A0.w*P0.w
                  + A1.x*P1.x + A1.y*P1.y + A1.z*P1.z + A1.w*P1.w;
        float rBm = B0.x*m0.x + B0.y*m0.y + B0.z*m0.z + B0.w*m0.w
                  + B1.x*m1.x + B1.y*m1.y + B1.z*m1.z + B1.w*m1.w;
        float rBP = B0.x*P0.x + B0.y*P0.y + B0.z*P0.z + B0.w*P0.w
                  + B1.x*P1.x + B1.y*P1.y + B1.z*P1.z + B1.w*P1.w;

        // r = Rs[a]·p_src - Rd[a]·p_dst ; p_src/p_dst resolved by side.
        float r  = isDst ? (rAP - rBm) : (rAm - rBP);
        float rr = isDst ? -r : r;   // sign of the transpose-side contribution

        av0 += (isDst ? B0.x : A0.x) * rr;
        av1 += (isDst ? B0.y : A0.y) * rr;
        av2 += (isDst ? B0.z : A0.z) * rr;
        av3 += (isDst ? B0.w : A0.w) * rr;
        av4 += (isDst ? B1.x : A1.x) * rr;
        av5 += (isDst ? B1.y : A1.y) * rr;
        av6 += (isDst ? B1.z : A1.z) * rr;
        av7 += (isDst ? B1.w : A1.w) * rr;
    }

    // Combine the two incidence slots (lane ^ 32).
    av0 += __shfl_xor(av0, 32);
    av1 += __shfl_xor(av1, 32);
    av2 += __shfl_xor(av2, 32);
    av3 += __shfl_xor(av3, 32);
    av4 += __shfl_xor(av4, 32);
    av5 += __shfl_xor(av5, 32);
    av6 += __shfl_xor(av6, 32);
    av7 += __shfl_xor(av7, 32);

    // Transpose-reduce over the 8-lane 'a' group: lane a ends with the full
    // sum of component a. Each stage keeps half the components, sends the
    // other half to the partner (all register indices compile-time).
    bool h4 = (a & 4) != 0;
    float k0 = h4 ? av4 : av0, q0 = h4 ? av0 : av4;
    float k1 = h4 ? av5 : av1, q1 = h4 ? av1 : av5;
    float k2 = h4 ? av6 : av2, q2 = h4 ? av2 : av6;
    float k3 = h4 ? av7 : av3, q3 = h4 ? av3 : av7;
    float w0 = k0 + __shfl_xor(q0, 4);
    float w1 = k1 + __shfl_xor(q1, 4);
    float w2 = k2 + __shfl_xor(q2, 4);
    float w3 = k3 + __shfl_xor(q3, 4);
    bool h2 = (a & 2) != 0;
    float t0 = h2 ? w2 : w0, u0 = h2 ? w0 : w2;
    float t1 = h2 ? w3 : w1, u1 = h2 ? w1 : w3;
    float x0 = t0 + __shfl_xor(u0, 2);
    float x1 = t1 + __shfl_xor(u1, 2);
    bool h1 = (a & 1) != 0;
    float yk = h1 ? x1 : x0, ys = h1 ? x0 : x1;
    float val = yk + __shfl_xor(ys, 1);

    if (lane < 32) {
        size_t o = ((size_t)b * M + m) * 8 + a;
        acc[o] = val;
        float base = (k == 1) ? poly[0] * c0[o] : out[o];
        out[o] = base + poly[k] * val;
    }
}

extern "C" void kernel_launch(void* const* d_in, const int* in_sizes, int n_in,
                              void* d_out, int out_size, void* d_ws, size_t ws_size,
                              hipStream_t stream) {
    const float* c0   = (const float*)d_in[0];
    const int*   src  = (const int*)d_in[1];
    const int*   dst  = (const int*)d_in[2];
    const float* Rs   = (const float*)d_in[3];
    const float* Rd   = (const float*)d_in[4];
    const float* poly = (const float*)d_in[5];
    float* out = (float*)d_out;

    const int B = 4, D = 8;
    const int E = in_sizes[1];
    const int M = in_sizes[0] / (B * D);
    const size_t nElem = (size_t)B * M * D;   // 1.6M floats = 6.4 MB

    // Workspace layout (~39.2 MB total):
    //   bufA, bufB : ping-pong p/acc buffers (6.4 MB each)
    //   idx        : 2E int2 incidence entries (25.6 MB)
    //   cnt/off/cur: M ints each (0.6 MB)
    float* bufA = (float*)d_ws;
    float* bufB = bufA + nElem;
    int2*  idx  = (int2*)(bufB + nElem);
    int*   cnt  = (int*)(idx + (size_t)2 * E);
    int*   off  = cnt + M;
    int*   cur  = off + M;

    hipMemsetAsync(cnt, 0, (size_t)M * sizeof(int), stream);
    int eb = (E + BLOCK - 1) / BLOCK;
    hist_kernel<<<eb, BLOCK, 0, stream>>>(src, dst, cnt, E);
    scan_kernel<<<1, BLOCK, 0, stream>>>(cnt, off, cur, M);
    fill_kernel<<<eb, BLOCK, 0, stream>>>(src, dst, cur, idx, E);
    // after fill_kernel: cur[m] == bucket end for node m

    long nThreads = (long)M * 64;
    int gb = (int)((nThreads + BLOCK - 1) / BLOCK);
    gather_kernel<<<gb, BLOCK, 0, stream>>>(c0,   Rs, Rd, off, cur, idx, poly, 1, c0, bufA, out, M);
    gather_kernel<<<gb, BLOCK, 0, stream>>>(bufA, Rs, Rd, off, cur, idx, poly, 2, c0, bufB, out, M);
    gather_kernel<<<gb, BLOCK, 0, stream>>>(bufB, Rs, Rd, off, cur, idx, poly, 3, c0, bufA, out, M);
}